// Round 2
// baseline (442.683 us; speedup 1.0000x reference)
//
#include <hip/hip_runtime.h>
#include <hip/hip_bf16.h>

// Sizes (fixed by the problem)
#define BB 32
#define TT 1500
#define DD 512
#define AA 512
#define HH 4
#define CC 10
#define KK 100
#define KW 201          // 2K+1
#define MM (BB*TT)      // 48000 GEMM rows

typedef unsigned short u16;
typedef __attribute__((ext_vector_type(8))) short  bf16x8;
typedef __attribute__((ext_vector_type(8))) unsigned short u16x8;
typedef __attribute__((ext_vector_type(4))) float  f32x4;

static __device__ __forceinline__ u16 f2bf(float f) {
    unsigned x = __float_as_uint(f);
    return (u16)((x + 0x7fffu + ((x >> 16) & 1u)) >> 16);   // RNE
}
static __device__ __forceinline__ float bf2f(u16 u) {
    return __uint_as_float(((unsigned)u) << 16);
}

// async global->LDS, 16B per lane (wave-uniform LDS base + lane*16)
static __device__ __forceinline__ void stage16(const void* g, void* l) {
#if __has_builtin(__builtin_amdgcn_global_load_lds)
    __builtin_amdgcn_global_load_lds(
        (const __attribute__((address_space(1))) void*)g,
        (__attribute__((address_space(3))) void*)l, 16, 0, 0);
#else
    *(u16x8*)l = *(const u16x8*)g;
#endif
}

// ---------------- key f32 -> bf16 (8 elems/thread) ----------------
__global__ __launch_bounds__(256) void cvt_key_k(const float* __restrict__ in,
                                                 u16* __restrict__ out) {
    int i = blockIdx.x * 256 + threadIdx.x;        // * 8 elements
    const float4* p = (const float4*)in + (size_t)i * 2;
    float4 x = p[0], y = p[1];
    u16x8 o;
    o[0] = f2bf(x.x); o[1] = f2bf(x.y); o[2] = f2bf(x.z); o[3] = f2bf(x.w);
    o[4] = f2bf(y.x); o[5] = f2bf(y.y); o[6] = f2bf(y.z); o[7] = f2bf(y.w);
    *((u16x8*)out + i) = o;
}

// ---------------- w_enc [D][A] f32 -> transposed bf16 [A][D] ----------------
__global__ __launch_bounds__(256) void cvt_wenc_k(const float* __restrict__ W,
                                                  u16* __restrict__ Wt) {
    __shared__ float tile[32][33];
    int a0 = blockIdx.x * 32, d0 = blockIdx.y * 32;
    int tx = threadIdx.x, ty = threadIdx.y;        // (32,8)
#pragma unroll
    for (int i = 0; i < 4; ++i)
        tile[ty + i * 8][tx] = W[(d0 + ty + i * 8) * AA + a0 + tx];  // tile[d][a]
    __syncthreads();
#pragma unroll
    for (int i = 0; i < 4; ++i)
        Wt[(a0 + ty + i * 8) * DD + d0 + tx] = f2bf(tile[tx][ty + i * 8]);
}

// ---------------- GEMM: key_a(bf16) = key(bf16)[M,K] @ wencT(bf16)[N,K]^T ----
// 128x128 tile, BK=32, 4 waves (2x2), 16x16x32 MFMA, global_load_lds staging,
// bijective XCD swizzle (m204; nwg=1500, q=187, r=4) for A-panel L2 reuse.
__global__ __launch_bounds__(256) void gemm_k(const u16* __restrict__ Abf,
                                              const u16* __restrict__ Bt,
                                              u16* __restrict__ Cbf) {
    __shared__ u16 sA[128 * 32];
    __shared__ u16 sB[128 * 32];
    int tid = threadIdx.x;
    int orig = blockIdx.x;                 // 0..1499, bn fast within bm
    int xcd = orig & 7, idx = orig >> 3;
    int swz = (xcd < 4 ? xcd * 188 : 752 + (xcd - 4) * 187) + idx;
    int bn = swz & 3;                      // 0..3
    int bm = swz >> 2;                     // 0..374
    int row0 = bm * 128, col0 = bn * 128;
    int lane = tid & 63, wv = tid >> 6;
    int wr = wv >> 1, wc = wv & 1;  // 2x2 waves, each owns 64x64 of C
    int lhi = lane >> 4, llo = lane & 15;

    f32x4 acc[4][4];
#pragma unroll
    for (int i = 0; i < 4; ++i)
#pragma unroll
        for (int j = 0; j < 4; ++j) acc[i][j] = (f32x4){0.f, 0.f, 0.f, 0.f};

    int er = tid >> 2;              // tile row (of 64 per staging pass)
    int ek = (tid & 3) * 8;         // k-offset (8 bf16 = 16B)
    const u16* ga0 = Abf + (size_t)(row0 + er) * DD + ek;
    const u16* gb0 = Bt  + (size_t)(col0 + er) * DD + ek;
    u16* lA = sA + tid * 8;
    u16* lB = sB + tid * 8;

    for (int k0 = 0; k0 < DD; k0 += 32) {
        __syncthreads();                              // prev compute done reading LDS
        stage16(ga0 + k0,            lA);             // A rows 0..63
        stage16(ga0 + 64 * DD + k0,  lA + 2048);      // A rows 64..127
        stage16(gb0 + k0,            lB);             // B(n) rows 0..63
        stage16(gb0 + 64 * DD + k0,  lB + 2048);      // B(n) rows 64..127
        __syncthreads();                              // compiler drains vmcnt here

        bf16x8 af[4], bfr[4];
#pragma unroll
        for (int i = 0; i < 4; ++i)
            af[i] = *(const bf16x8*)(sA + (wr * 64 + i * 16 + llo) * 32 + lhi * 8);
#pragma unroll
        for (int j = 0; j < 4; ++j)
            bfr[j] = *(const bf16x8*)(sB + (wc * 64 + j * 16 + llo) * 32 + lhi * 8);
#pragma unroll
        for (int i = 0; i < 4; ++i)
#pragma unroll
            for (int j = 0; j < 4; ++j)
                acc[i][j] = __builtin_amdgcn_mfma_f32_16x16x32_bf16(
                    af[i], bfr[j], acc[i][j], 0, 0, 0);
    }
    // C/D layout: row = (lane>>4)*4 + r, col = lane&15  (m89-verified)
#pragma unroll
    for (int i = 0; i < 4; ++i) {
#pragma unroll
        for (int j = 0; j < 4; ++j) {
            int gr = row0 + wr * 64 + i * 16 + lhi * 4;
            int gc = col0 + wc * 64 + j * 16 + llo;
#pragma unroll
            for (int r = 0; r < 4; ++r)
                Cbf[(size_t)(gr + r) * AA + gc] = f2bf(acc[i][j][r]);
        }
    }
}

// ---------------- dec[b][a] = query[b]·w_dec[:,a] + w_enc_b[a] ----------------
__global__ __launch_bounds__(256) void dec_k(const float* __restrict__ q,
                                             const float* __restrict__ wdec,
                                             const float* __restrict__ encb,
                                             float* __restrict__ dec) {
    int b = blockIdx.x;
    int a = blockIdx.y * 256 + threadIdx.x;
    __shared__ float sq[DD];
    for (int i = threadIdx.x; i < DD; i += 256) sq[i] = q[b * DD + i];
    __syncthreads();
    float acc = encb[a];
#pragma unroll 8
    for (int d = 0; d < DD; ++d) acc += sq[d] * wdec[d * AA + a];
    dec[b * AA + a] = acc;
}

// ---------------- grouped conv1d: cf[h][b][t][c] ----------------
// 2 blocks per (h,b) (T halves of 750); 3 consecutive t per thread, register ring
__global__ __launch_bounds__(256) void conv_k(const float* __restrict__ aw,
                                              const float* __restrict__ cW,
                                              float* __restrict__ cf) {
    int half = blockIdx.x & 1, hb = blockIdx.x >> 1;
    int h = hb >> 5, b = hb & 31;
    __shared__ float srow[952];     // [tstart-100 .. tstart+850), zero-padded halo
    __shared__ float swk[CC * KW];  // this head's 10x201 kernel
    int tid = threadIdx.x;
    int tstart = half * 750;
    const float* arow = aw + (h * BB + b) * TT;
    for (int i = tid; i < 952; i += 256) {
        int t = tstart + i - KK;
        srow[i] = (t >= 0 && t < TT) ? arow[t] : 0.f;
    }
    for (int i = tid; i < CC * KW; i += 256) swk[i] = cW[h * CC * KW + i];
    __syncthreads();
    if (tid >= 250) return;
    int tl = tid * 3;
    float acc[CC][3];
#pragma unroll
    for (int c = 0; c < CC; ++c)
#pragma unroll
        for (int u = 0; u < 3; ++u) acc[c][u] = 0.f;
    float r0 = srow[tl], r1 = srow[tl + 1], r2 = srow[tl + 2];
    for (int j = 0; j < KW; ++j) {
#pragma unroll
        for (int c = 0; c < CC; ++c) {
            float w = swk[c * KW + j];
            acc[c][0] += r0 * w; acc[c][1] += r1 * w; acc[c][2] += r2 * w;
        }
        r0 = r1; r1 = r2; r2 = srow[tl + j + 3];
    }
    float* dst = cf + ((size_t)(h * BB + b) * TT + tstart + tl) * CC;
#pragma unroll
    for (int u = 0; u < 3; ++u)
#pragma unroll
        for (int c = 0; c < CC; ++c) dst[u * CC + c] = acc[c][u];
}

// ---------------- e[h][b][t] = v · tanh(key_a + dec + cf@w_conv) ----------------
// Σ_a v·tanh(x_a) = Σ_a v[a] − Σ_a 2v[a]·rcp(1+exp(2x_a))  (saves abs/copysign/sub)
// one wave handles 4 t; all 4 heads fused; params LDS-fill amortized over 16 t/block
__global__ __launch_bounds__(256) void e_k(const u16* __restrict__ keya,
                                           const float* __restrict__ dec,
                                           const float* __restrict__ cf,
                                           const float* __restrict__ wconv,
                                           const float* __restrict__ vw,
                                           float* __restrict__ e) {
    int b = blockIdx.y;
    int tid = threadIdx.x, lane = tid & 63, wv = tid >> 6;
    __shared__ float sdec[AA], sv2[AA], swc[CC * AA];
    for (int i = tid; i < AA; i += 256) { sdec[i] = dec[b * AA + i]; sv2[i] = 2.f * vw[i]; }
    for (int i = tid; i < CC * AA; i += 256) swc[i] = wconv[i];
    __syncthreads();
    float S_lane = 0.f;                        // Σ v[a] over this lane's a-slots
#pragma unroll
    for (int it = 0; it < 8; ++it) S_lane += 0.5f * sv2[it * 64 + lane];
    int t0 = blockIdx.x * 16 + wv * 4;
    for (int u = 0; u < 4; ++u) {
        int t = t0 + u;
        if (t >= TT) break;
        float cfh[HH][CC];
#pragma unroll
        for (int h = 0; h < HH; ++h) {
            const float* cp = cf + ((size_t)(h * BB + b) * TT + t) * CC;
#pragma unroll
            for (int c = 0; c < CC; ++c) cfh[h][c] = cp[c];
        }
        const u16* ka = keya + (size_t)(b * TT + t) * AA;
        float acc[HH] = {0.f, 0.f, 0.f, 0.f};   // Σ 2v·rcp(1+exp(2x))
        for (int it = 0; it < 8; ++it) {
            int a = it * 64 + lane;
            float kv = bf2f(ka[a]) + sdec[a];
            float v2 = sv2[a];
            float wcr[CC];
#pragma unroll
            for (int c = 0; c < CC; ++c) wcr[c] = swc[c * AA + a];
#pragma unroll
            for (int h = 0; h < HH; ++h) {
                float cpv = 0.f;
#pragma unroll
                for (int c = 0; c < CC; ++c) cpv += cfh[h][c] * wcr[c];
                float x = kv + cpv;
                float z = exp2f(x * 2.8853900817779268f);   // exp(2x)
                float r = __builtin_amdgcn_rcpf(1.f + z);
                acc[h] += v2 * r;
            }
        }
#pragma unroll
        for (int h = 0; h < HH; ++h) {
            float s = S_lane - acc[h];
#pragma unroll
            for (int off = 32; off; off >>= 1) s += __shfl_xor(s, off);
            if (lane == 0) e[(size_t)(h * BB + b) * TT + t] = s;
        }
    }
}

// ---------------- masked softmax over T per (h,b) row ----------------
__global__ __launch_bounds__(256) void softmax_k(const float* __restrict__ e,
                                                 const int* __restrict__ klen,
                                                 float* __restrict__ o) {
    int h = blockIdx.x >> 5, b = blockIdx.x & 31;
    int len = klen[b];                         // >= 3T/4, never 0
    const float* er = e + (size_t)(h * BB + b) * TT;
    float* orow = o + (size_t)(h * BB + b) * TT;
    __shared__ float sp[TT];
    __shared__ float rbuf[8];
    int tid = threadIdx.x, lane = tid & 63, wv = tid >> 6;
    float mx = -3.4e38f;
    for (int t = tid; t < len; t += 256) mx = fmaxf(mx, er[t]);
#pragma unroll
    for (int off = 32; off; off >>= 1) mx = fmaxf(mx, __shfl_xor(mx, off));
    if (lane == 0) rbuf[wv] = mx;
    __syncthreads();
    mx = fmaxf(fmaxf(rbuf[0], rbuf[1]), fmaxf(rbuf[2], rbuf[3]));
    float sum = 0.f;
    for (int t = tid; t < len; t += 256) {
        float p = __expf(er[t] - mx);
        sp[t] = p; sum += p;
    }
#pragma unroll
    for (int off = 32; off; off >>= 1) sum += __shfl_xor(sum, off);
    if (lane == 0) rbuf[4 + wv] = sum;
    __syncthreads();
    float inv = 1.f / (rbuf[4] + rbuf[5] + rbuf[6] + rbuf[7]);
    for (int t = tid; t < TT; t += 256) orow[t] = (t < len) ? sp[t] * inv : 0.f;
}

// ---------------- ctx[b][h][v] = sum_t aw[h,b,t] * value[b,t,v] ----------------
// grid (B, 25 t-chunks of 60), atomics into zeroed ctx
__global__ __launch_bounds__(512) void ctx_k(const float* __restrict__ aw,
                                             const float* __restrict__ value,
                                             float* __restrict__ ctx) {
    int b = blockIdx.x, c0 = blockIdx.y * 60;
    int tid = threadIdx.x;
    __shared__ float sw[HH][60];
    if (tid < HH * 60) sw[tid / 60][tid % 60] = aw[(size_t)((tid / 60) * BB + b) * TT + c0 + (tid % 60)];
    __syncthreads();
    float a0 = 0, a1 = 0, a2 = 0, a3 = 0;
    const float* vp = value + ((size_t)b * TT + c0) * DD + tid;
    for (int t = 0; t < 60; ++t) {
        float val = vp[(size_t)t * DD];
        a0 += sw[0][t] * val; a1 += sw[1][t] * val;
        a2 += sw[2][t] * val; a3 += sw[3][t] * val;
    }
    atomicAdd(&ctx[(b * HH + 0) * DD + tid], a0);
    atomicAdd(&ctx[(b * HH + 1) * DD + tid], a1);
    atomicAdd(&ctx[(b * HH + 2) * DD + tid], a2);
    atomicAdd(&ctx[(b * HH + 3) * DD + tid], a3);
}

// ---------------- out[b][d] = ctx_flat[b]·w_out[:,d] + b_out[d] ----------------
// grid (B/4, 32 k-chunks of 64), atomics into zeroed out
__global__ __launch_bounds__(512) void out_k(const float* __restrict__ ctx,
                                             const float* __restrict__ wout,
                                             const float* __restrict__ wob,
                                             float* __restrict__ out) {
    int b0 = blockIdx.x * 4, kc = blockIdx.y;
    int tid = threadIdx.x;                      // = d
    __shared__ float sc[4][64];
    if (tid < 256) sc[tid >> 6][tid & 63] = ctx[(size_t)(b0 + (tid >> 6)) * (HH * DD) + kc * 64 + (tid & 63)];
    __syncthreads();
    float acc0 = 0, acc1 = 0, acc2 = 0, acc3 = 0;
    const float* wp = wout + (size_t)(kc * 64) * DD + tid;
#pragma unroll 8
    for (int kk = 0; kk < 64; ++kk) {
        float w = wp[(size_t)kk * DD];
        acc0 += sc[0][kk] * w; acc1 += sc[1][kk] * w;
        acc2 += sc[2][kk] * w; acc3 += sc[3][kk] * w;
    }
    if (kc == 0) {
        float bb = wob[tid];
        acc0 += bb; acc1 += bb; acc2 += bb; acc3 += bb;
    }
    atomicAdd(&out[(b0 + 0) * DD + tid], acc0);
    atomicAdd(&out[(b0 + 1) * DD + tid], acc1);
    atomicAdd(&out[(b0 + 2) * DD + tid], acc2);
    atomicAdd(&out[(b0 + 3) * DD + tid], acc3);
}

extern "C" void kernel_launch(void* const* d_in, const int* in_sizes, int n_in,
                              void* d_out, int out_size, void* d_ws, size_t ws_size,
                              hipStream_t stream) {
    const float* key    = (const float*)d_in[0];
    const int*   klen   = (const int*)  d_in[1];
    const float* value  = (const float*)d_in[2];
    const float* query  = (const float*)d_in[3];
    const float* aw     = (const float*)d_in[4];
    const float* wencW  = (const float*)d_in[5];
    const float* wencb  = (const float*)d_in[6];
    const float* wdecW  = (const float*)d_in[7];
    const float* wconvW = (const float*)d_in[8];
    const float* vW     = (const float*)d_in[9];
    const float* convW  = (const float*)d_in[10];
    const float* woutW  = (const float*)d_in[11];
    const float* woutb  = (const float*)d_in[12];

    float* out    = (float*)d_out;                  // [B*D]
    float* aw_new = out + BB * DD;                  // [H*B*T]

    // workspace layout (~107.6 MB total)
    char* ws = (char*)d_ws;
    u16*   key_bf = (u16*)ws;                                   // 49,152,000 B
    u16*   wenc_t = (u16*)(ws + 49152000);                      //    524,288 B
    u16*   keya   = (u16*)(ws + 49676288);                      // 49,152,000 B (bf16 key_a)
    float* dec    = (float*)(ws + 98828288);                    //     65,536 B
    float* cfeat  = (float*)(ws + 98893824);                    //  7,680,000 B
    float* e      = (float*)(ws + 106573824);                   //    768,000 B
    float* ctx    = (float*)(ws + 107341824);                   //    262,144 B

    hipMemsetAsync(out, 0, BB * DD * sizeof(float), stream);
    hipMemsetAsync(ctx, 0, BB * HH * DD * sizeof(float), stream);

    cvt_key_k <<<MM * DD / (256 * 8), 256, 0, stream>>>(key, key_bf);
    cvt_wenc_k<<<dim3(16, 16), dim3(32, 8), 0, stream>>>(wencW, wenc_t);
    gemm_k    <<<1500, 256, 0, stream>>>(key_bf, wenc_t, keya);
    dec_k     <<<dim3(BB, 2), 256, 0, stream>>>(query, wdecW, wencb, dec);
    conv_k    <<<HH * BB * 2, 256, 0, stream>>>(aw, convW, cfeat);
    e_k       <<<dim3((TT + 15) / 16, BB), 256, 0, stream>>>(keya, dec, cfeat, wconvW, vW, e);
    softmax_k <<<HH * BB, 256, 0, stream>>>(e, klen, aw_new);
    ctx_k     <<<dim3(BB, 25), 512, 0, stream>>>(aw, value, ctx);
    out_k     <<<dim3(BB / 4, 32), 512, 0, stream>>>(ctx, woutW, woutb, out);
}

// Round 3
// 440.426 us; speedup vs baseline: 1.0051x; 1.0051x over previous
//
#include <hip/hip_runtime.h>
#include <hip/hip_bf16.h>

// Sizes (fixed by the problem)
#define BB 32
#define TT 1500
#define DD 512
#define AA 512
#define HH 4
#define CC 10
#define KK 100
#define KW 201          // 2K+1
#define MM (BB*TT)      // 48000 GEMM rows

#define PRESCALE 2.8853900817779268f   // 2/ln(2): tanh(x) = 1 - 2*rcp(1+exp2(PS*x))

typedef unsigned short u16;
typedef __attribute__((ext_vector_type(8))) short  bf16x8;
typedef __attribute__((ext_vector_type(8))) unsigned short u16x8;
typedef __attribute__((ext_vector_type(4))) float  f32x4;

static __device__ __forceinline__ u16 f2bf(float f) {
    unsigned x = __float_as_uint(f);
    return (u16)((x + 0x7fffu + ((x >> 16) & 1u)) >> 16);   // RNE
}

// async global->LDS, 16B per lane (wave-uniform LDS base + lane*16)
static __device__ __forceinline__ void stage16(const void* g, void* l) {
#if __has_builtin(__builtin_amdgcn_global_load_lds)
    __builtin_amdgcn_global_load_lds(
        (const __attribute__((address_space(1))) void*)g,
        (__attribute__((address_space(3))) void*)l, 16, 0, 0);
#else
    *(u16x8*)l = *(const u16x8*)g;
#endif
}

// ---------------- key f32 -> bf16 (8 elems/thread) ----------------
__global__ __launch_bounds__(256) void cvt_key_k(const float* __restrict__ in,
                                                 u16* __restrict__ out) {
    int i = blockIdx.x * 256 + threadIdx.x;        // * 8 elements
    const float4* p = (const float4*)in + (size_t)i * 2;
    float4 x = p[0], y = p[1];
    u16x8 o;
    o[0] = f2bf(x.x); o[1] = f2bf(x.y); o[2] = f2bf(x.z); o[3] = f2bf(x.w);
    o[4] = f2bf(y.x); o[5] = f2bf(y.y); o[6] = f2bf(y.z); o[7] = f2bf(y.w);
    *((u16x8*)out + i) = o;
}

// ---------------- w_enc [D][A] f32 -> transposed bf16 [A][D] ----------------
__global__ __launch_bounds__(256) void cvt_wenc_k(const float* __restrict__ W,
                                                  u16* __restrict__ Wt) {
    __shared__ float tile[32][33];
    int a0 = blockIdx.x * 32, d0 = blockIdx.y * 32;
    int tx = threadIdx.x, ty = threadIdx.y;        // (32,8)
#pragma unroll
    for (int i = 0; i < 4; ++i)
        tile[ty + i * 8][tx] = W[(d0 + ty + i * 8) * AA + a0 + tx];  // tile[d][a]
    __syncthreads();
#pragma unroll
    for (int i = 0; i < 4; ++i)
        Wt[(a0 + ty + i * 8) * DD + d0 + tx] = f2bf(tile[tx][ty + i * 8]);
}

// ---------------- dec[b][a] = query[b]·w_dec[:,a] + w_enc_b[a] ----------------
__global__ __launch_bounds__(256) void dec_k(const float* __restrict__ q,
                                             const float* __restrict__ wdec,
                                             const float* __restrict__ encb,
                                             float* __restrict__ dec) {
    int b = blockIdx.x;
    int a = blockIdx.y * 256 + threadIdx.x;
    __shared__ float sq[DD];
    for (int i = threadIdx.x; i < DD; i += 256) sq[i] = q[b * DD + i];
    __syncthreads();
    float acc = encb[a];
#pragma unroll 8
    for (int d = 0; d < DD; ++d) acc += sq[d] * wdec[d * AA + a];
    dec[b * AA + a] = acc;
}

// ---------------- grouped conv1d: cf[h][b*T+t][c] ----------------
// 2 blocks per (h,b) (T halves of 750); 3 consecutive t per thread, register ring
__global__ __launch_bounds__(256) void conv_k(const float* __restrict__ aw,
                                              const float* __restrict__ cW,
                                              float* __restrict__ cf) {
    int half = blockIdx.x & 1, hb = blockIdx.x >> 1;
    int h = hb >> 5, b = hb & 31;
    __shared__ float srow[952];     // [tstart-100 .. tstart+850), zero-padded halo
    __shared__ float swk[CC * KW];  // this head's 10x201 kernel
    int tid = threadIdx.x;
    int tstart = half * 750;
    const float* arow = aw + (h * BB + b) * TT;
    for (int i = tid; i < 952; i += 256) {
        int t = tstart + i - KK;
        srow[i] = (t >= 0 && t < TT) ? arow[t] : 0.f;
    }
    for (int i = tid; i < CC * KW; i += 256) swk[i] = cW[h * CC * KW + i];
    __syncthreads();
    if (tid >= 250) return;
    int tl = tid * 3;
    float acc[CC][3];
#pragma unroll
    for (int c = 0; c < CC; ++c)
#pragma unroll
        for (int u = 0; u < 3; ++u) acc[c][u] = 0.f;
    float r0 = srow[tl], r1 = srow[tl + 1], r2 = srow[tl + 2];
    for (int j = 0; j < KW; ++j) {
#pragma unroll
        for (int c = 0; c < CC; ++c) {
            float w = swk[c * KW + j];
            acc[c][0] += r0 * w; acc[c][1] += r1 * w; acc[c][2] += r2 * w;
        }
        r0 = r1; r1 = r2; r2 = srow[tl + j + 3];
    }
    float* dst = cf + ((size_t)h * MM + (size_t)b * TT + tstart + tl) * CC;
#pragma unroll
    for (int u = 0; u < 3; ++u)
#pragma unroll
        for (int c = 0; c < CC; ++c) dst[u * CC + c] = acc[c][u];
}

// ---------------- fused GEMM + e-epilogue -------------------------------------
// key_a tile = key(bf16)[M,K] @ wencT(bf16)[N,K]^T  (128x128 tile, BK=32, 2x2 waves)
// epilogue: x = (acc + dec)·PS + cf·(wconv·PS);  Q[h,row] += Σ_col v·rcp(1+exp2(x))
// (softmax consumes e = -2·Q; the Σv constant cancels in softmax)
__global__ __launch_bounds__(256) void gemm_e_k(const u16* __restrict__ Abf,
                                                const u16* __restrict__ Bt,
                                                const float* __restrict__ dec,
                                                const float* __restrict__ cf,
                                                const float* __restrict__ wconv,
                                                const float* __restrict__ vw,
                                                float* __restrict__ Q) {
    // union LDS: K-loop uses 16 KB (sA/sB); epilogue uses 26.75 KB
    __shared__ float smem[6848];
    u16* sA = (u16*)smem;                 // [128*32] bf16 = 8 KB
    u16* sB = (u16*)smem + 4096;          // 8 KB
    float* scf   = smem;                  // [4][128][10] = 20480 B
    float* sdec2 = smem + 5120;           // [2][128]
    float* ssv   = smem + 5376;           // [128]
    float* sswc  = smem + 5504;           // [10][128] (pre-scaled by PS)

    int tid = threadIdx.x;
    int orig = blockIdx.x;                 // 0..1499
    int xcd = orig & 7, idx = orig >> 3;   // bijective m204 swizzle (q=187, r=4)
    int swz = (xcd < 4 ? xcd * 188 : 752 + (xcd - 4) * 187) + idx;
    int bn = swz & 3;
    int bm = swz >> 2;                     // 0..374
    int row0 = bm * 128, col0 = bn * 128;
    int lane = tid & 63, wv = tid >> 6;
    int wr = wv >> 1, wc = wv & 1;         // 2x2 waves, each owns 64x64 of C
    int lhi = lane >> 4, llo = lane & 15;

    f32x4 acc[4][4];
#pragma unroll
    for (int i = 0; i < 4; ++i)
#pragma unroll
        for (int j = 0; j < 4; ++j) acc[i][j] = (f32x4){0.f, 0.f, 0.f, 0.f};

    int er = tid >> 2;              // staging row (64 per pass)
    int ek = (tid & 3) * 8;         // k-offset (8 bf16 = 16B)
    const u16* ga0 = Abf + (size_t)(row0 + er) * DD + ek;
    const u16* gb0 = Bt  + (size_t)(col0 + er) * DD + ek;
    u16* lA = sA + tid * 8;
    u16* lB = sB + tid * 8;

    for (int k0 = 0; k0 < DD; k0 += 32) {
        __syncthreads();
        stage16(ga0 + k0,            lA);
        stage16(ga0 + 64 * DD + k0,  lA + 2048);
        stage16(gb0 + k0,            lB);
        stage16(gb0 + 64 * DD + k0,  lB + 2048);
        __syncthreads();

        bf16x8 af[4], bfr[4];
#pragma unroll
        for (int i = 0; i < 4; ++i)
            af[i] = *(const bf16x8*)(sA + (wr * 64 + i * 16 + llo) * 32 + lhi * 8);
#pragma unroll
        for (int j = 0; j < 4; ++j)
            bfr[j] = *(const bf16x8*)(sB + (wc * 64 + j * 16 + llo) * 32 + lhi * 8);
#pragma unroll
        for (int i = 0; i < 4; ++i)
#pragma unroll
            for (int j = 0; j < 4; ++j)
                acc[i][j] = __builtin_amdgcn_mfma_f32_16x16x32_bf16(
                    af[i], bfr[j], acc[i][j], 0, 0, 0);
    }

    // ---------------- epilogue ----------------
    __syncthreads();                       // all waves done with sA/sB
    {
        int b0 = row0 / TT;
        int b1c = min(b0 + 1, BB - 1);
        // stage cf rows [row0, row0+128) for all 4 heads: 1280 float4
        const float4* cfg = (const float4*)(cf);
        float4* scf4 = (float4*)scf;
        for (int i = tid; i < 1280; i += 256) {
            int h = i / 320, rem = i - h * 320;         // 320 float4 per head
            scf4[h * 320 + rem] = cfg[((size_t)h * MM + row0) * 10 / 4 + rem];
        }
        if (tid < 128) {
            sdec2[tid]       = dec[b0  * AA + col0 + tid];
            sdec2[128 + tid] = dec[b1c * AA + col0 + tid];
            ssv[tid] = vw[col0 + tid];
        }
        for (int i = tid; i < 1280; i += 256) {
            int c = i >> 7, col = i & 127;
            sswc[i] = wconv[c * AA + col0 + col] * PRESCALE;
        }
    }
    __syncthreads();

    int b0 = row0 / TT;
    int boundary = (b0 + 1) * TT - row0;   // local row >= boundary -> batch b0+1
    // per-lane column constants (4 cols)
    float wcr2[4][10], svj[4], d0j[4], d1j[4];
#pragma unroll
    for (int j = 0; j < 4; ++j) {
        int col = wc * 64 + j * 16 + llo;
        svj[j] = ssv[col];
        d0j[j] = sdec2[col];
        d1j[j] = sdec2[128 + col];
#pragma unroll
        for (int c = 0; c < 10; ++c) wcr2[j][c] = sswc[c * 128 + col];
    }

#pragma unroll
    for (int i = 0; i < 4; ++i) {
#pragma unroll
        for (int r = 0; r < 4; ++r) {
            int lr = wr * 64 + i * 16 + lhi * 4 + r;
            bool hi = lr >= boundary;
            // cf for this row, all 4 heads (float2 LDS reads, rows are 40B apart)
            float2 cfh[4][5];
#pragma unroll
            for (int h = 0; h < 4; ++h) {
                const float2* cp = (const float2*)(scf + (h * 128 + lr) * 10);
#pragma unroll
                for (int c = 0; c < 5; ++c) cfh[h][c] = cp[c];
            }
            float x0s[4];
#pragma unroll
            for (int j = 0; j < 4; ++j)
                x0s[j] = (acc[i][j][r] + (hi ? d1j[j] : d0j[j])) * PRESCALE;
            float epart[4] = {0.f, 0.f, 0.f, 0.f};
#pragma unroll
            for (int h = 0; h < 4; ++h) {
#pragma unroll
                for (int j = 0; j < 4; ++j) {
                    float arg = x0s[j];
#pragma unroll
                    for (int c = 0; c < 5; ++c) {
                        arg = fmaf(cfh[h][c].x, wcr2[j][2 * c],     arg);
                        arg = fmaf(cfh[h][c].y, wcr2[j][2 * c + 1], arg);
                    }
                    float z = exp2f(arg);
                    float rr = __builtin_amdgcn_rcpf(1.f + z);
                    epart[h] = fmaf(svj[j], rr, epart[h]);
                }
            }
            int grow = row0 + lr;
#pragma unroll
            for (int h = 0; h < 4; ++h) {
                float s = epart[h];
                s += __shfl_xor(s, 1);
                s += __shfl_xor(s, 2);
                s += __shfl_xor(s, 4);
                s += __shfl_xor(s, 8);
                if (llo == 0) atomicAdd(&Q[(size_t)h * MM + grow], s);
            }
        }
    }
}

// ---------------- masked softmax over T per (h,b) row: e = -2*Q ----------------
__global__ __launch_bounds__(256) void softmax_k(const float* __restrict__ Qb,
                                                 const int* __restrict__ klen,
                                                 float* __restrict__ o) {
    int h = blockIdx.x >> 5, b = blockIdx.x & 31;
    int len = klen[b];                         // >= 3T/4, never 0
    const float* er = Qb + (size_t)h * MM + (size_t)b * TT;
    float* orow = o + (size_t)(h * BB + b) * TT;
    __shared__ float sp[TT];
    __shared__ float rbuf[8];
    int tid = threadIdx.x, lane = tid & 63, wv = tid >> 6;
    float mx = -3.4e38f;
    for (int t = tid; t < len; t += 256) mx = fmaxf(mx, -2.f * er[t]);
#pragma unroll
    for (int off = 32; off; off >>= 1) mx = fmaxf(mx, __shfl_xor(mx, off));
    if (lane == 0) rbuf[wv] = mx;
    __syncthreads();
    mx = fmaxf(fmaxf(rbuf[0], rbuf[1]), fmaxf(rbuf[2], rbuf[3]));
    float sum = 0.f;
    for (int t = tid; t < len; t += 256) {
        float p = __expf(-2.f * er[t] - mx);
        sp[t] = p; sum += p;
    }
#pragma unroll
    for (int off = 32; off; off >>= 1) sum += __shfl_xor(sum, off);
    if (lane == 0) rbuf[4 + wv] = sum;
    __syncthreads();
    float inv = 1.f / (rbuf[4] + rbuf[5] + rbuf[6] + rbuf[7]);
    for (int t = tid; t < TT; t += 256) orow[t] = (t < len) ? sp[t] * inv : 0.f;
}

// ---------------- ctx[b][h][v] = sum_t aw[h,b,t] * value[b,t,v] ----------------
__global__ __launch_bounds__(512) void ctx_k(const float* __restrict__ aw,
                                             const float* __restrict__ value,
                                             float* __restrict__ ctx) {
    int b = blockIdx.x, c0 = blockIdx.y * 60;
    int tid = threadIdx.x;
    __shared__ float sw[HH][60];
    if (tid < HH * 60) sw[tid / 60][tid % 60] = aw[(size_t)((tid / 60) * BB + b) * TT + c0 + (tid % 60)];
    __syncthreads();
    float a0 = 0, a1 = 0, a2 = 0, a3 = 0;
    const float* vp = value + ((size_t)b * TT + c0) * DD + tid;
    for (int t = 0; t < 60; ++t) {
        float val = vp[(size_t)t * DD];
        a0 += sw[0][t] * val; a1 += sw[1][t] * val;
        a2 += sw[2][t] * val; a3 += sw[3][t] * val;
    }
    atomicAdd(&ctx[(b * HH + 0) * DD + tid], a0);
    atomicAdd(&ctx[(b * HH + 1) * DD + tid], a1);
    atomicAdd(&ctx[(b * HH + 2) * DD + tid], a2);
    atomicAdd(&ctx[(b * HH + 3) * DD + tid], a3);
}

// ---------------- out[b][d] = ctx_flat[b]·w_out[:,d] + b_out[d] ----------------
__global__ __launch_bounds__(512) void out_k(const float* __restrict__ ctx,
                                             const float* __restrict__ wout,
                                             const float* __restrict__ wob,
                                             float* __restrict__ out) {
    int b0 = blockIdx.x * 4, kc = blockIdx.y;
    int tid = threadIdx.x;                      // = d
    __shared__ float sc[4][64];
    if (tid < 256) sc[tid >> 6][tid & 63] = ctx[(size_t)(b0 + (tid >> 6)) * (HH * DD) + kc * 64 + (tid & 63)];
    __syncthreads();
    float acc0 = 0, acc1 = 0, acc2 = 0, acc3 = 0;
    const float* wp = wout + (size_t)(kc * 64) * DD + tid;
#pragma unroll 8
    for (int kk = 0; kk < 64; ++kk) {
        float w = wp[(size_t)kk * DD];
        acc0 += sc[0][kk] * w; acc1 += sc[1][kk] * w;
        acc2 += sc[2][kk] * w; acc3 += sc[3][kk] * w;
    }
    if (kc == 0) {
        float bb = wob[tid];
        acc0 += bb; acc1 += bb; acc2 += bb; acc3 += bb;
    }
    atomicAdd(&out[(b0 + 0) * DD + tid], acc0);
    atomicAdd(&out[(b0 + 1) * DD + tid], acc1);
    atomicAdd(&out[(b0 + 2) * DD + tid], acc2);
    atomicAdd(&out[(b0 + 3) * DD + tid], acc3);
}

extern "C" void kernel_launch(void* const* d_in, const int* in_sizes, int n_in,
                              void* d_out, int out_size, void* d_ws, size_t ws_size,
                              hipStream_t stream) {
    const float* key    = (const float*)d_in[0];
    const int*   klen   = (const int*)  d_in[1];
    const float* value  = (const float*)d_in[2];
    const float* query  = (const float*)d_in[3];
    const float* aw     = (const float*)d_in[4];
    const float* wencW  = (const float*)d_in[5];
    const float* wencb  = (const float*)d_in[6];
    const float* wdecW  = (const float*)d_in[7];
    const float* wconvW = (const float*)d_in[8];
    const float* vW     = (const float*)d_in[9];
    const float* convW  = (const float*)d_in[10];
    const float* woutW  = (const float*)d_in[11];
    const float* woutb  = (const float*)d_in[12];

    float* out    = (float*)d_out;                  // [B*D]
    float* aw_new = out + BB * DD;                  // [H*B*T]

    // workspace layout (~58.5 MB total)
    char* ws = (char*)d_ws;
    u16*   key_bf = (u16*)ws;                                   // 49,152,000 B
    u16*   wenc_t = (u16*)(ws + 49152000);                      //    524,288 B
    float* dec    = (float*)(ws + 49676288);                    //     65,536 B
    float* cfeat  = (float*)(ws + 49741824);                    //  7,680,000 B
    float* Q      = (float*)(ws + 57421824);                    //    768,000 B
    float* ctx    = (float*)(ws + 58189824);                    //    262,144 B

    hipMemsetAsync(out, 0, BB * DD * sizeof(float), stream);
    hipMemsetAsync(ctx, 0, BB * HH * DD * sizeof(float), stream);
    hipMemsetAsync(Q, 0, (size_t)HH * MM * sizeof(float), stream);

    cvt_key_k <<<MM * DD / (256 * 8), 256, 0, stream>>>(key, key_bf);
    cvt_wenc_k<<<dim3(16, 16), dim3(32, 8), 0, stream>>>(wencW, wenc_t);
    dec_k     <<<dim3(BB, 2), 256, 0, stream>>>(query, wdecW, wencb, dec);
    conv_k    <<<HH * BB * 2, 256, 0, stream>>>(aw, convW, cfeat);
    gemm_e_k  <<<1500, 256, 0, stream>>>(key_bf, wenc_t, dec, cfeat, wconvW, vW, Q);
    softmax_k <<<HH * BB, 256, 0, stream>>>(Q, klen, aw_new);
    ctx_k     <<<dim3(BB, 25), 512, 0, stream>>>(aw, value, ctx);
    out_k     <<<dim3(BB / 4, 32), 512, 0, stream>>>(ctx, woutW, woutb, out);
}

// Round 4
// 347.180 us; speedup vs baseline: 1.2751x; 1.2686x over previous
//
#include <hip/hip_runtime.h>
#include <hip/hip_bf16.h>

#define BB 32
#define TT 1500
#define DD 512
#define AA 512
#define HH 4
#define CC 10
#define KK 100
#define KW 201
#define MM (BB*TT)
#define PS 2.8853900817779268f   // 2/ln2: tanh(x) = 1 - 2*rcp(1+exp2(PS*x))

typedef unsigned short u16;
typedef unsigned int u32;
typedef __attribute__((ext_vector_type(8))) short bf16x8;
typedef __attribute__((ext_vector_type(4))) float f32x4;
typedef __attribute__((ext_vector_type(4))) unsigned int u32x4;

static __device__ __forceinline__ u16 f2bf(float f) {
    u32 x = __float_as_uint(f);
    return (u16)((x + 0x7fffu + ((x >> 16) & 1u)) >> 16);   // RNE
}
static __device__ __forceinline__ u32 pkbf(float lo, float hi) {
    u32 r;
    asm("v_cvt_pk_bf16_f32 %0, %1, %2" : "=v"(r) : "v"(lo), "v"(hi));
    return r;
}
static __device__ __forceinline__ void stage16(const void* g, void* l) {
    __builtin_amdgcn_global_load_lds(
        (const __attribute__((address_space(1))) void*)g,
        (__attribute__((address_space(3))) void*)l, 16, 0, 0);
}

// =================== prep: wencT(+PS), dec_ps, conv, zero ctx/out ===========
__global__ __launch_bounds__(256) void prep_k(
    const float* __restrict__ wencW, const float* __restrict__ q,
    const float* __restrict__ wdec, const float* __restrict__ encb,
    const float* __restrict__ aw, const float* __restrict__ convW,
    u16* __restrict__ wenc_t, float* __restrict__ dec_ps,
    float* __restrict__ cfeat, float* __restrict__ ctx, float* __restrict__ outz)
{
    __shared__ float pls[4160];
    int blk = blockIdx.x, tid = threadIdx.x;
    if (blk < 64) {
        // transpose + PS-scale w_enc -> bf16 [A][D], 64x64 tile per block
        int a0 = (blk & 7) * 64, d0 = (blk >> 3) * 64;
#pragma unroll
        for (int it = 0; it < 16; ++it) {
            int row = it * 4 + (tid >> 6), col = tid & 63;
            pls[row * 65 + col] = wencW[(size_t)(d0 + row) * AA + a0 + col];
        }
        __syncthreads();
#pragma unroll
        for (int it = 0; it < 16; ++it) {
            int ar = it * 4 + (tid >> 6), dc = tid & 63;
            wenc_t[(size_t)(a0 + ar) * DD + d0 + dc] = f2bf(pls[dc * 65 + ar] * PS);
        }
    } else if (blk < 128) {
        // dec_ps[b][a] = PS*(encb[a] + q[b]·wdec[:,a])
        int bidx = blk - 64;
        int b = bidx >> 1, a = (bidx & 1) * 256 + tid;
        for (int i = tid; i < DD; i += 256) pls[i] = q[b * DD + i];
        __syncthreads();
        float acc = encb[a];
#pragma unroll 8
        for (int d = 0; d < DD; ++d) acc = fmaf(pls[d], wdec[(size_t)d * AA + a], acc);
        dec_ps[b * AA + a] = acc * PS;
    } else if (blk < 384) {
        // grouped conv1d -> cfeat[h][b*T+t][10]; 2 blocks per (h,b)
        int cidx = blk - 128;
        int half = cidx & 1, hb = cidx >> 1;
        int h = hb >> 5, b = hb & 31;
        float* srow = pls;            // 952
        float* swk  = pls + 952;      // 2010
        int tstart = half * 750;
        const float* arow = aw + (size_t)(h * BB + b) * TT;
        for (int i = tid; i < 952; i += 256) {
            int t = tstart + i - KK;
            srow[i] = (t >= 0 && t < TT) ? arow[t] : 0.f;
        }
        for (int i = tid; i < CC * KW; i += 256) swk[i] = convW[h * CC * KW + i];
        __syncthreads();
        if (tid < 250) {
            int tl = tid * 3;
            float acc[CC][3];
#pragma unroll
            for (int c = 0; c < CC; ++c)
#pragma unroll
                for (int u = 0; u < 3; ++u) acc[c][u] = 0.f;
            float r0 = srow[tl], r1 = srow[tl + 1], r2 = srow[tl + 2];
            for (int j = 0; j < KW; ++j) {
#pragma unroll
                for (int c = 0; c < CC; ++c) {
                    float w = swk[c * KW + j];
                    acc[c][0] = fmaf(r0, w, acc[c][0]);
                    acc[c][1] = fmaf(r1, w, acc[c][1]);
                    acc[c][2] = fmaf(r2, w, acc[c][2]);
                }
                r0 = r1; r1 = r2; r2 = srow[tl + j + 3];
            }
            float* dst = cfeat + ((size_t)h * MM + (size_t)b * TT + tstart + tl) * CC;
#pragma unroll
            for (int u = 0; u < 3; ++u)
#pragma unroll
                for (int c = 0; c < CC; ++c) dst[u * CC + c] = acc[c][u];
        }
    } else if (blk < 392) {
        // zero ctx: 16384 float4
        float4* p = (float4*)ctx;
        int bidx = blk - 384;
        float4 z = {0.f, 0.f, 0.f, 0.f};
#pragma unroll
        for (int k2 = 0; k2 < 8; ++k2) p[bidx * 2048 + k2 * 256 + tid] = z;
    } else {
        // zero out: 4096 float4
        float4* p = (float4*)outz;
        int bidx = blk - 392;
        float4 z = {0.f, 0.f, 0.f, 0.f};
#pragma unroll
        for (int k2 = 0; k2 < 8; ++k2) p[bidx * 2048 + k2 * 256 + tid] = z;
    }
}

// =================== fused GEMM + head-MFMA + e-epilogue ====================
// acc = PS*(key·wenc) via 16 K-steps (A reg-staged f32->bf16, B global_load_lds)
// per head: t4 = mfma([cf|sel], [wconvPS|decPS], acc) = PS*x
// epilogue: Q4[bn][h][row] = sum_col v * rcp(1+exp2(t4))   (plain stores)
__global__ __launch_bounds__(256) void gemm_e_k(
    const float* __restrict__ key, const u16* __restrict__ Bt,
    const float* __restrict__ dec_ps, const float* __restrict__ cf,
    const float* __restrict__ wconv, const float* __restrict__ vw,
    float* __restrict__ Q4)
{
    __shared__ float smf[5128];          // 20512 B union
    char* smem = (char*)smf;
    u16* sB = (u16*)(smem + 10240);      // main: sA [128][40]bf16 @0, sB [128][32]bf16
    u16* sAe = (u16*)smem;               // epi: [4][128][16]bf16 @0
    u16* sBe = (u16*)(smem + 16384);     // epi: [128][16]bf16
    const int ZPAD = 20480;              // 16B zeros for lhi>=2 fragment reads

    int tid = threadIdx.x;
    int orig = blockIdx.x;
    int xcd = orig & 7, idx = orig >> 3;               // bijective m204 swizzle
    int swz = (xcd < 4 ? xcd * 188 : 752 + (xcd - 4) * 187) + idx;
    int bn = swz & 3, bm = swz >> 2;
    int row0 = bm * 128, col0 = bn * 128;
    int lane = tid & 63, wv = tid >> 6;
    int wr = wv >> 1, wc = wv & 1;
    int lhi = lane >> 4, llo = lane & 15;

    f32x4 acc[4][4];
#pragma unroll
    for (int i = 0; i < 4; ++i)
#pragma unroll
        for (int j = 0; j < 4; ++j) acc[i][j] = (f32x4){0.f, 0.f, 0.f, 0.f};

    // A staging: thread = (row=tid>>1, 16-float half=tid&1)
    const float4* gA = (const float4*)(key + (size_t)(row0 + (tid >> 1)) * DD) + (tid & 1) * 4;
    u32 aWoff = (tid >> 1) * 80 + (tid & 1) * 32;
    // B staging: global_load_lds, linear
    const u16* gB0 = Bt + (size_t)(col0 + (tid >> 2)) * DD + (tid & 3) * 8;
    u16* lB = sB + tid * 8;

    float4 pa0 = gA[0], pa1 = gA[1], pa2 = gA[2], pa3 = gA[3];
    for (int k0 = 0; k0 < DD; k0 += 32) {
        __syncthreads();
        stage16(gB0 + k0, lB);
        stage16(gB0 + 64 * DD + k0, lB + 2048);
        u32x4 s0, s1;
        s0.x = pkbf(pa0.x, pa0.y); s0.y = pkbf(pa0.z, pa0.w);
        s0.z = pkbf(pa1.x, pa1.y); s0.w = pkbf(pa1.z, pa1.w);
        s1.x = pkbf(pa2.x, pa2.y); s1.y = pkbf(pa2.z, pa2.w);
        s1.z = pkbf(pa3.x, pa3.y); s1.w = pkbf(pa3.z, pa3.w);
        *(u32x4*)(smem + aWoff) = s0;
        *(u32x4*)(smem + aWoff + 16) = s1;
        if (k0 + 32 < DD) {
            int nb = (k0 + 32) >> 2;
            pa0 = gA[nb]; pa1 = gA[nb + 1]; pa2 = gA[nb + 2]; pa3 = gA[nb + 3];
        }
        __syncthreads();

        bf16x8 af[4], bfr[4];
#pragma unroll
        for (int i = 0; i < 4; ++i)
            af[i] = *(const bf16x8*)(smem + (wr * 64 + i * 16 + llo) * 80 + lhi * 16);
#pragma unroll
        for (int j = 0; j < 4; ++j)
            bfr[j] = *(const bf16x8*)(sB + (wc * 64 + j * 16 + llo) * 32 + lhi * 8);
#pragma unroll
        for (int i = 0; i < 4; ++i)
#pragma unroll
            for (int j = 0; j < 4; ++j)
                acc[i][j] = __builtin_amdgcn_mfma_f32_16x16x32_bf16(
                    af[i], bfr[j], acc[i][j], 0, 0, 0);
    }

    // ---- stage extension tiles ----
    __syncthreads();
    int b0 = row0 / TT;
    int boundary = (b0 + 1) * TT - row0;
    int b1 = min(b0 + 1, BB - 1);
    {
        // sAe[h][128 rows][16k]: k0..9=cf, k10=sel_b0, k11=sel_b1, k12..15=0
        int h = tid >> 6;
#pragma unroll
        for (int e = 0; e < 2; ++e) {
            int r = (tid & 63) * 2 + e;
            const float2* cp = (const float2*)(cf + ((size_t)h * MM + row0 + r) * CC);
            float2 c0 = cp[0], c1 = cp[1], c2 = cp[2], c3 = cp[3], c4 = cp[4];
            u32x4 lo, hi;
            lo.x = pkbf(c0.x, c0.y); lo.y = pkbf(c1.x, c1.y);
            lo.z = pkbf(c2.x, c2.y); lo.w = pkbf(c3.x, c3.y);
            hi.x = pkbf(c4.x, c4.y);
            hi.y = (r < boundary) ? 0x00003f80u : 0x3f800000u;  // (sel0,sel1) bf16
            hi.z = 0u; hi.w = 0u;
            char* dst = smem + (h * 128 + r) * 32;
            *(u32x4*)dst = lo;
            *(u32x4*)(dst + 16) = hi;
        }
        // sBe[128 cols][16k]: k0..9=wconv*PS, k10=dec_ps[b0], k11=dec_ps[b1], k12..15=0
        int col = tid >> 1, kh = tid & 1;
        u32x4 w;
        if (kh == 0) {
            float v0 = wconv[0 * AA + col0 + col] * PS, v1 = wconv[1 * AA + col0 + col] * PS;
            float v2 = wconv[2 * AA + col0 + col] * PS, v3 = wconv[3 * AA + col0 + col] * PS;
            float v4 = wconv[4 * AA + col0 + col] * PS, v5 = wconv[5 * AA + col0 + col] * PS;
            float v6 = wconv[6 * AA + col0 + col] * PS, v7 = wconv[7 * AA + col0 + col] * PS;
            w.x = pkbf(v0, v1); w.y = pkbf(v2, v3); w.z = pkbf(v4, v5); w.w = pkbf(v6, v7);
        } else {
            float v8 = wconv[8 * AA + col0 + col] * PS, v9 = wconv[9 * AA + col0 + col] * PS;
            float d0v = dec_ps[b0 * AA + col0 + col], d1v = dec_ps[b1 * AA + col0 + col];
            w.x = pkbf(v8, v9); w.y = pkbf(d0v, d1v); w.z = 0u; w.w = 0u;
        }
        *(u32x4*)((char*)sBe + col * 32 + kh * 16) = w;
        if (tid == 0) { *(u32x4*)(smem + ZPAD) = (u32x4){0u, 0u, 0u, 0u}; }
    }
    __syncthreads();

    // ---- head-steps + epilogue ----
    float svj[4];
    bf16x8 be[4];
#pragma unroll
    for (int j = 0; j < 4; ++j) {
        int col = wc * 64 + j * 16 + llo;
        svj[j] = vw[col0 + col];
        u32 off = (lhi < 2) ? (16384u + col * 32 + lhi * 16) : (u32)ZPAD;
        be[j] = *(const bf16x8*)(smem + off);
    }
#pragma unroll
    for (int h = 0; h < 4; ++h) {
#pragma unroll
        for (int i = 0; i < 4; ++i) {
            int rowA = h * 128 + wr * 64 + i * 16 + llo;
            u32 offa = (lhi < 2) ? (rowA * 32 + lhi * 16) : (u32)ZPAD;
            bf16x8 ae = *(const bf16x8*)(smem + offa);
            float ep[4] = {0.f, 0.f, 0.f, 0.f};
#pragma unroll
            for (int j = 0; j < 4; ++j) {
                f32x4 t4 = __builtin_amdgcn_mfma_f32_16x16x32_bf16(ae, be[j], acc[i][j], 0, 0, 0);
#pragma unroll
                for (int r = 0; r < 4; ++r) {
                    float z = exp2f(t4[r]);
                    float p = __builtin_amdgcn_rcpf(1.f + z);
                    ep[r] = fmaf(svj[j], p, ep[r]);
                }
            }
#pragma unroll
            for (int r = 0; r < 4; ++r) {
                float s = ep[r];
                s += __shfl_xor(s, 1);
                s += __shfl_xor(s, 2);
                s += __shfl_xor(s, 4);
                s += __shfl_xor(s, 8);
                if (llo == 0)
                    Q4[((size_t)(bn * HH + h)) * MM + row0 + wr * 64 + i * 16 + lhi * 4 + r] = s;
            }
        }
    }
}

// =================== fin: softmax (blk<128) | ctx (blk>=128) =================
__global__ __launch_bounds__(256) void fin_k(
    const float* __restrict__ Q4, const int* __restrict__ klen,
    const float* __restrict__ aw, const float* __restrict__ value,
    float* __restrict__ aw_new, float* __restrict__ ctx)
{
    __shared__ float fls[1512];
    int blk = blockIdx.x, tid = threadIdx.x;
    if (blk < 128) {
        int h = blk >> 5, b = blk & 31;
        int len = klen[b];
        const float* q0 = Q4 + (size_t)(0 * HH + h) * MM + (size_t)b * TT;
        const float* q1 = Q4 + (size_t)(1 * HH + h) * MM + (size_t)b * TT;
        const float* q2 = Q4 + (size_t)(2 * HH + h) * MM + (size_t)b * TT;
        const float* q3 = Q4 + (size_t)(3 * HH + h) * MM + (size_t)b * TT;
        float* orow = aw_new + (size_t)(h * BB + b) * TT;
        float* rbuf = fls + 1500;
        int lane = tid & 63, wvv = tid >> 6;
        float mx = -3.4e38f;
        for (int t = tid; t < len; t += 256) {
            float e = -2.f * (q0[t] + q1[t] + q2[t] + q3[t]);
            fls[t] = e;
            mx = fmaxf(mx, e);
        }
#pragma unroll
        for (int off = 32; off; off >>= 1) mx = fmaxf(mx, __shfl_xor(mx, off));
        if (lane == 0) rbuf[wvv] = mx;
        __syncthreads();
        mx = fmaxf(fmaxf(rbuf[0], rbuf[1]), fmaxf(rbuf[2], rbuf[3]));
        float sum = 0.f;
        for (int t = tid; t < len; t += 256) {
            float p = __expf(fls[t] - mx);
            fls[t] = p; sum += p;
        }
#pragma unroll
        for (int off = 32; off; off >>= 1) sum += __shfl_xor(sum, off);
        if (lane == 0) rbuf[4 + wvv] = sum;
        __syncthreads();
        float inv = 1.f / (rbuf[4] + rbuf[5] + rbuf[6] + rbuf[7]);
        for (int t = tid; t < TT; t += 256) orow[t] = (t < len) ? fls[t] * inv : 0.f;
    } else {
        int cidx = blk - 128;
        int b = cidx / 25, chunk = cidx - b * 25;
        int c0 = chunk * 60;
        float (*sw)[60] = (float(*)[60])fls;
        if (tid < 240)
            sw[tid / 60][tid % 60] = aw[(size_t)((tid / 60) * BB + b) * TT + c0 + (tid % 60)];
        __syncthreads();
        float a00 = 0, a01 = 0, a10 = 0, a11 = 0, a20 = 0, a21 = 0, a30 = 0, a31 = 0;
        const float* vp = value + ((size_t)b * TT + c0) * DD;
        for (int t = 0; t < 60; ++t) {
            float v0 = vp[(size_t)t * DD + tid];
            float v1 = vp[(size_t)t * DD + tid + 256];
            a00 = fmaf(sw[0][t], v0, a00); a01 = fmaf(sw[0][t], v1, a01);
            a10 = fmaf(sw[1][t], v0, a10); a11 = fmaf(sw[1][t], v1, a11);
            a20 = fmaf(sw[2][t], v0, a20); a21 = fmaf(sw[2][t], v1, a21);
            a30 = fmaf(sw[3][t], v0, a30); a31 = fmaf(sw[3][t], v1, a31);
        }
        atomicAdd(&ctx[(b * HH + 0) * DD + tid], a00);
        atomicAdd(&ctx[(b * HH + 0) * DD + tid + 256], a01);
        atomicAdd(&ctx[(b * HH + 1) * DD + tid], a10);
        atomicAdd(&ctx[(b * HH + 1) * DD + tid + 256], a11);
        atomicAdd(&ctx[(b * HH + 2) * DD + tid], a20);
        atomicAdd(&ctx[(b * HH + 2) * DD + tid + 256], a21);
        atomicAdd(&ctx[(b * HH + 3) * DD + tid], a30);
        atomicAdd(&ctx[(b * HH + 3) * DD + tid + 256], a31);
    }
}

// =================== out[b][d] = ctx_flat[b]·w_out[:,d] + b_out[d] ==========
__global__ __launch_bounds__(512) void out_k(const float* __restrict__ ctx,
                                             const float* __restrict__ wout,
                                             const float* __restrict__ wob,
                                             float* __restrict__ out)
{
    int b0 = blockIdx.x * 4, kc = blockIdx.y;
    int tid = threadIdx.x;
    __shared__ float sc[4][64];
    if (tid < 256) sc[tid >> 6][tid & 63] =
        ctx[(size_t)(b0 + (tid >> 6)) * (HH * DD) + kc * 64 + (tid & 63)];
    __syncthreads();
    float acc0 = 0, acc1 = 0, acc2 = 0, acc3 = 0;
    const float* wp = wout + (size_t)(kc * 64) * DD + tid;
#pragma unroll 8
    for (int kk = 0; kk < 64; ++kk) {
        float w = wp[(size_t)kk * DD];
        acc0 = fmaf(sc[0][kk], w, acc0); acc1 = fmaf(sc[1][kk], w, acc1);
        acc2 = fmaf(sc[2][kk], w, acc2); acc3 = fmaf(sc[3][kk], w, acc3);
    }
    if (kc == 0) {
        float bb = wob[tid];
        acc0 += bb; acc1 += bb; acc2 += bb; acc3 += bb;
    }
    atomicAdd(&out[(b0 + 0) * DD + tid], acc0);
    atomicAdd(&out[(b0 + 1) * DD + tid], acc1);
    atomicAdd(&out[(b0 + 2) * DD + tid], acc2);
    atomicAdd(&out[(b0 + 3) * DD + tid], acc3);
}

extern "C" void kernel_launch(void* const* d_in, const int* in_sizes, int n_in,
                              void* d_out, int out_size, void* d_ws, size_t ws_size,
                              hipStream_t stream) {
    const float* key    = (const float*)d_in[0];
    const int*   klen   = (const int*)  d_in[1];
    const float* value  = (const float*)d_in[2];
    const float* query  = (const float*)d_in[3];
    const float* aw     = (const float*)d_in[4];
    const float* wencW  = (const float*)d_in[5];
    const float* wencb  = (const float*)d_in[6];
    const float* wdecW  = (const float*)d_in[7];
    const float* wconvW = (const float*)d_in[8];
    const float* vW     = (const float*)d_in[9];
    const float* convW  = (const float*)d_in[10];
    const float* woutW  = (const float*)d_in[11];
    const float* woutb  = (const float*)d_in[12];

    float* out    = (float*)d_out;                  // [B*D]
    float* aw_new = out + BB * DD;                  // [H*B*T]

    // workspace (~11.6 MB)
    char* ws = (char*)d_ws;
    u16*   wenc_t = (u16*)ws;                       //   524,288 B
    float* dec_ps = (float*)(ws + 524288);          //    65,536 B
    float* cfeat  = (float*)(ws + 589824);          // 7,680,000 B
    float* Q4     = (float*)(ws + 8269824);         // 3,072,000 B
    float* ctx    = (float*)(ws + 11341824);        //   262,144 B

    prep_k  <<<394, 256, 0, stream>>>(wencW, query, wdecW, wencb, aw, convW,
                                      wenc_t, dec_ps, cfeat, ctx, out);
    gemm_e_k<<<1500, 256, 0, stream>>>(key, wenc_t, dec_ps, cfeat, wconvW, vW, Q4);
    fin_k   <<<928, 256, 0, stream>>>(Q4, klen, aw, value, aw_new, ctx);
    out_k   <<<dim3(8, 32), 512, 0, stream>>>(ctx, woutW, woutb, out);
}